// Round 1
// baseline (1899.720 us; speedup 1.0000x reference)
//
#include <hip/hip_runtime.h>

// Problem constants (from reference setup_inputs)
#define DIN 200   // fc_out in_features
#define DH  100   // fc_out out_features (= fc_cat in_features)
#define RG  32    // rows per register group (per wave)
#define KC  40    // k-chunk staged in LDS
#define NC  5     // DIN / KC
#define JP  128   // padded j dimension (2 j-slots per lane)
#define MARGIN 2e-3f  // conservative fp32 worst-case error bound on delta

__device__ inline float wave_sum_f32(float v) {
#pragma unroll
  for (int m = 1; m < 64; m <<= 1) v += __shfl_xor(v, m, 64);
  return v;
}
__device__ inline double wave_sum_f64(double v) {
#pragma unroll
  for (int m = 1; m < 64; m <<= 1) v += __shfl_xor(v, m, 64);
  return v;
}

__global__ __launch_bounds__(256, 3)
void entmax_sign_kernel(const float* __restrict__ x,
                        const float* __restrict__ w_out,
                        const float* __restrict__ b_out,
                        const float* __restrict__ w_cat,
                        const float* __restrict__ b_cat,
                        const float* __restrict__ w2,
                        const float* __restrict__ b2,
                        float* __restrict__ out, int N)
{
  // Transposed w chunk: wsT[kk][j], stride 128 floats -> bank = j%32 (2-way, free)
  __shared__ float ws[KC * JP];   // 40*128*4 = 20 KB

  const int tid  = threadIdx.x;
  const int lane = tid & 63;
  const long long wave = (long long)blockIdx.x * 4 + (tid >> 6);
  const int rowbase = (int)(wave * 64);

  const int j0 = lane;        // always < 100
  const int j1 = lane + 64;   // valid only if < 100
  const float dw0 = w_cat[j0] - w_cat[DH + j0];
  const float b0  = b_out[j0];
  const float dw1 = (j1 < DH) ? (w_cat[j1] - w_cat[DH + j1]) : 0.f;
  const float b1  = (j1 < DH) ? b_out[j1] : 0.f;
  const float db  = b_cat[0] - b_cat[1];
  const float c0  = w2[0] + b2[0];
  const float c1  = w2[1] + b2[0];

  // Zero entire ws once: pad region (j in [100,128)) must read as 0.
  // First __syncthreads below orders this before any read.
  for (int t = tid; t < KC * JP; t += 256) ws[t] = 0.f;

  const char* xb = (const char*)x;

  for (int g = 0; g < 2; ++g) {
    const int rowT = rowbase + g * RG;
    float h0[RG], h1[RG];
#pragma unroll
    for (int r = 0; r < RG; ++r) { h0[r] = 0.f; h1[r] = 0.f; }

    for (int c = 0; c < NC; ++c) {
      __syncthreads();  // previous chunk's reads done
      // Stage w chunk c transposed: coalesced float4 global read, 4x b32 LDS scatter
      for (int e4 = tid; e4 < DH * (KC / 4); e4 += 256) {
        const int j  = e4 / (KC / 4);
        const int kk = (e4 - j * (KC / 4)) * 4;
        float4 v = *(const float4*)(w_out + j * DIN + c * KC + kk);
        ws[(kk + 0) * JP + j] = v.x;
        ws[(kk + 1) * JP + j] = v.y;
        ws[(kk + 2) * JP + j] = v.z;
        ws[(kk + 3) * JP + j] = v.w;
      }
      __syncthreads();  // chunk staged

      unsigned boff[RG];
#pragma unroll
      for (int r = 0; r < RG; ++r) {
        int rr = rowT + r; if (rr >= N) rr = N - 1;   // clamp (N is a multiple of 256 anyway)
        boff[r] = (unsigned)((rr * DIN + c * KC) * 4);
      }

#pragma unroll 1
      for (int k4 = 0; k4 < KC / 4; ++k4) {
        // w fragments for this k4 (reused across 32 rows)
        float w0x = ws[(4 * k4 + 0) * JP + j0];
        float w0y = ws[(4 * k4 + 1) * JP + j0];
        float w0z = ws[(4 * k4 + 2) * JP + j0];
        float w0w = ws[(4 * k4 + 3) * JP + j0];
        float w1x = ws[(4 * k4 + 0) * JP + j1];
        float w1y = ws[(4 * k4 + 1) * JP + j1];
        float w1z = ws[(4 * k4 + 2) * JP + j1];
        float w1w = ws[(4 * k4 + 3) * JP + j1];
#pragma unroll
        for (int r = 0; r < RG; ++r) {
          float4 xv = *(const float4*)(xb + boff[r]);
          boff[r] += 16;
          h0[r] = fmaf(xv.x, w0x, h0[r]);
          h0[r] = fmaf(xv.y, w0y, h0[r]);
          h0[r] = fmaf(xv.z, w0z, h0[r]);
          h0[r] = fmaf(xv.w, w0w, h0[r]);
          h1[r] = fmaf(xv.x, w1x, h1[r]);
          h1[r] = fmaf(xv.y, w1y, h1[r]);
          h1[r] = fmaf(xv.z, w1z, h1[r]);
          h1[r] = fmaf(xv.w, w1w, h1[r]);
        }
      }
    }

    // Epilogue: per-row relu + weighted reduce + sign decision
#pragma unroll 1
    for (int r = 0; r < RG; ++r) {
      const int row = rowT + r;
      float t0 = fmaxf(h0[r] + b0, 0.f);
      float t1 = fmaxf(h1[r] + b1, 0.f);
      float t  = t0 * dw0 + t1 * dw1;
      float delta = wave_sum_f32(t) + db;   // identical on all 64 lanes (butterfly)
      bool pick0;
      if (fabsf(delta) < MARGIN) {
        // Near boundary: exact float64 recompute of this row (rare, ~0.2% of rows)
        const int rsafe = (row < N) ? row : (N - 1);
        const float* xr = x + (long long)rsafe * DIN;
        double a0 = 0.0, a1 = 0.0;
        for (int k = 0; k < DIN; ++k) {
          double xd = (double)xr[k];
          a0 += xd * (double)w_out[j0 * DIN + k];
          if (j1 < DH) a1 += xd * (double)w_out[j1 * DIN + k];
        }
        double u0 = a0 + (double)b0; u0 = (u0 > 0.0) ? u0 : 0.0;
        double u1 = a1 + (double)b1; u1 = (u1 > 0.0) ? u1 : 0.0;
        double td = u0 * (double)dw0 + u1 * (double)dw1;
        double sd = wave_sum_f64(td) + ((double)b_cat[0] - (double)b_cat[1]);
        pick0 = (sd >= 0.0);
      } else {
        pick0 = (delta >= 0.0f);
      }
      if (lane == 0 && row < N) out[row] = pick0 ? c0 : c1;
    }
  }
}

extern "C" void kernel_launch(void* const* d_in, const int* in_sizes, int n_in,
                              void* d_out, int out_size, void* d_ws, size_t ws_size,
                              hipStream_t stream) {
  const float* x     = (const float*)d_in[0];
  const float* w_out = (const float*)d_in[1];
  const float* b_out = (const float*)d_in[2];
  const float* w_cat = (const float*)d_in[3];
  const float* b_cat = (const float*)d_in[4];
  const float* w2    = (const float*)d_in[5];
  const float* b2    = (const float*)d_in[6];
  float* out = (float*)d_out;

  const int N = in_sizes[0] / DIN;          // 524288
  const int nblk = (N + 255) / 256;         // 256 rows per block (4 waves x 64)
  entmax_sign_kernel<<<nblk, 256, 0, stream>>>(x, w_out, b_out, w_cat, b_cat,
                                               w2, b2, out, N);
}

// Round 2
// 502.018 us; speedup vs baseline: 3.7842x; 3.7842x over previous
//
#include <hip/hip_runtime.h>

// Problem constants (from reference setup_inputs)
#define DIN 200    // fc_out in_features (K)
#define DH  100    // fc_out out_features (J)
#define RT  256    // rows per block tile
#define RT_P 258   // padded row stride in xs (bank spread for staging writes)
#define KC  40     // k-chunk staged in LDS
#define NC  5      // DIN / KC
#define R   4      // rows per lane
#define JW  25     // j columns per wave
#define MARGIN 2e-4f

__device__ inline double wave_sum_f64(double v) {
#pragma unroll
  for (int m = 1; m < 64; m <<= 1) v += __shfl_xor(v, m, 64);
  return v;
}

__device__ double fp64_delta_row(const float* __restrict__ x,
                                 const float* __restrict__ w_out,
                                 const float* __restrict__ b_out,
                                 const float* __restrict__ w_cat,
                                 const float* __restrict__ b_cat,
                                 int row, int lane) {
  const float* xr = x + (size_t)row * DIN;
  const int j0 = lane, j1 = lane + 64;
  double a0 = 0.0, a1 = 0.0;
  for (int k = 0; k < DIN; ++k) {
    double xd = (double)xr[k];
    a0 += xd * (double)w_out[j0 * DIN + k];
    if (j1 < DH) a1 += xd * (double)w_out[j1 * DIN + k];
  }
  double t = 0.0;
  {
    double u = a0 + (double)b_out[j0];
    if (u > 0.0) t += u * ((double)w_cat[j0] - (double)w_cat[DH + j0]);
  }
  if (j1 < DH) {
    double u = a1 + (double)b_out[j1];
    if (u > 0.0) t += u * ((double)w_cat[j1] - (double)w_cat[DH + j1]);
  }
  t = wave_sum_f64(t);
  return t + ((double)b_cat[0] - (double)b_cat[1]);
}

__global__ __launch_bounds__(256, 3)
void entmax_sign_kernel(const float* __restrict__ x,
                        const float* __restrict__ w_out,
                        const float* __restrict__ b_out,
                        const float* __restrict__ w_cat,
                        const float* __restrict__ b_cat,
                        const float* __restrict__ w2,
                        const float* __restrict__ b2,
                        float* __restrict__ out, int N) {
  __shared__ float xs[KC * RT_P];      // transposed x chunk: xs[k][row], 41280 B
  __shared__ float parts[4][RT];       // per-wave j-partials, 4096 B

  const int tid  = threadIdx.x;
  const int lane = tid & 63;
  // readfirstlane forces wave-uniform (SGPR) -> w loads become s_load_dwordx4
  const int wid   = __builtin_amdgcn_readfirstlane(tid >> 6);
  const int jbase = wid * JW;
  const int row0  = blockIdx.x * RT;   // N = 524288 is a multiple of RT

  const float db = b_cat[0] - b_cat[1];
  const float c0 = w2[0] + b2[0];
  const float c1 = w2[1] + b2[0];

  float acc[R][JW];
#pragma unroll
  for (int ri = 0; ri < R; ++ri)
#pragma unroll
    for (int jj = 0; jj < JW; ++jj) acc[ri][jj] = 0.f;

  const float* xg0 = x + (size_t)row0 * DIN;

#pragma unroll 1
  for (int c = 0; c < NC; ++c) {
    __syncthreads();  // previous chunk's reads complete
    // ---- stage x chunk (transposed) ----
    {
      int idx = tid;
#pragma unroll
      for (int it = 0; it < (RT * (KC / 4)) / 256; ++it, idx += 256) {
        const int row = idx / (KC / 4);
        const int kq  = idx - row * (KC / 4);
        float4 v = *(const float4*)(xg0 + row * DIN + c * KC + kq * 4);
        xs[(kq * 4 + 0) * RT_P + row] = v.x;
        xs[(kq * 4 + 1) * RT_P + row] = v.y;
        xs[(kq * 4 + 2) * RT_P + row] = v.z;
        xs[(kq * 4 + 3) * RT_P + row] = v.w;
      }
    }
    __syncthreads();  // chunk staged

    const float* wp = w_out + jbase * DIN + c * KC;  // wave-uniform pointer

#pragma unroll 1
    for (int kq = 0; kq < KC / 4; ++kq) {
      float xr[R][4];
#pragma unroll
      for (int ri = 0; ri < R; ++ri)
#pragma unroll
        for (int e = 0; e < 4; ++e)
          xr[ri][e] = xs[(kq * 4 + e) * RT_P + lane + 64 * ri];

#pragma unroll
      for (int jj = 0; jj < JW; ++jj) {
        const float4 wv = *(const float4*)(wp + jj * DIN + kq * 4);  // s_load
#pragma unroll
        for (int ri = 0; ri < R; ++ri) {
          acc[ri][jj] = fmaf(xr[ri][0], wv.x, acc[ri][jj]);
          acc[ri][jj] = fmaf(xr[ri][1], wv.y, acc[ri][jj]);
          acc[ri][jj] = fmaf(xr[ri][2], wv.z, acc[ri][jj]);
          acc[ri][jj] = fmaf(xr[ri][3], wv.w, acc[ri][jj]);
        }
      }
    }
  }

  // ---- epilogue: relu + dw-weighted partial over this wave's 25 j ----
  float part[R];
#pragma unroll
  for (int ri = 0; ri < R; ++ri) part[ri] = 0.f;
#pragma unroll
  for (int jj = 0; jj < JW; ++jj) {
    const int j = jbase + jj;
    const float bj = b_out[j];                       // uniform (s_load)
    const float dj = w_cat[j] - w_cat[DH + j];       // uniform (s_load)
#pragma unroll
    for (int ri = 0; ri < R; ++ri)
      part[ri] += fmaxf(acc[ri][jj] + bj, 0.f) * dj;
  }
#pragma unroll
  for (int ri = 0; ri < R; ++ri) parts[wid][lane + 64 * ri] = part[ri];
  __syncthreads();

  // thread tid owns row_in_tile = tid (its wave id == wid)
  const float delta = parts[0][tid] + parts[1][tid] + parts[2][tid] + parts[3][tid] + db;
  const float val = (delta >= 0.f) ? c0 : c1;
  const bool flag = fabsf(delta) < MARGIN;
  if (!flag) out[row0 + tid] = val;

  unsigned long long mask = __ballot(flag);
  while (mask) {
    const int b = __ffsll((unsigned long long)mask) - 1;
    mask &= mask - 1;
    const int row = row0 + (wid << 6) + b;
    const double s = fp64_delta_row(x, w_out, b_out, w_cat, b_cat, row, lane);
    if (lane == 0) out[row] = (s >= 0.0) ? c0 : c1;
  }
}

extern "C" void kernel_launch(void* const* d_in, const int* in_sizes, int n_in,
                              void* d_out, int out_size, void* d_ws, size_t ws_size,
                              hipStream_t stream) {
  const float* x     = (const float*)d_in[0];
  const float* w_out = (const float*)d_in[1];
  const float* b_out = (const float*)d_in[2];
  const float* w_cat = (const float*)d_in[3];
  const float* b_cat = (const float*)d_in[4];
  const float* w2    = (const float*)d_in[5];
  const float* b2    = (const float*)d_in[6];
  float* out = (float*)d_out;

  const int N = in_sizes[0] / DIN;      // 524288
  const int nblk = N / RT;              // 2048
  entmax_sign_kernel<<<nblk, 256, 0, stream>>>(x, w_out, b_out, w_cat, b_cat,
                                               w2, b2, out, N);
}